// Round 8
// baseline (286.450 us; speedup 1.0000x reference)
//
#include <hip/hip_runtime.h>
#include <stdint.h>

using u16 = unsigned short;
typedef __bf16 bf16x8 __attribute__((ext_vector_type(8)));
typedef __bf16 bf16x2 __attribute__((ext_vector_type(2)));
typedef float f32x4 __attribute__((ext_vector_type(4)));

// B=4, C=256, H=W=64, NH=8, D=32, 3x3 window
#define NPIX 16384   // B*H*W
#define CDIM 256

__device__ __forceinline__ float b2f(u16 u) {
  union { unsigned i; float f; } c; c.i = ((unsigned)u) << 16; return c.f;
}
__device__ __forceinline__ u16 f2b(float x) {
  union { __bf16 h; u16 u; } c; c.h = (__bf16)x; return c.u;
}
__device__ __forceinline__ unsigned pack2(float a, float b) {
  union { bf16x2 v; unsigned u; } c; c.v[0] = (__bf16)a; c.v[1] = (__bf16)b; return c.u;
}
__device__ __forceinline__ void unpack8(uint4 w, float* f) {
  f[0] = b2f((u16)(w.x & 0xffffu)); f[1] = b2f((u16)(w.x >> 16));
  f[2] = b2f((u16)(w.y & 0xffffu)); f[3] = b2f((u16)(w.y >> 16));
  f[4] = b2f((u16)(w.z & 0xffffu)); f[5] = b2f((u16)(w.z >> 16));
  f[6] = b2f((u16)(w.w & 0xffffu)); f[7] = b2f((u16)(w.w >> 16));
}

// async global->LDS DMA, 16 B/lane.
__device__ __forceinline__ void async16(u16* l, const u16* g) {
  __builtin_amdgcn_global_load_lds((const __attribute__((address_space(1))) void*)g,
                                   (__attribute__((address_space(3))) void*)l, 16, 0, 0);
}

// Stage rows x 64ch (bf16) from row-major [*,256] source into linear LDS
// [rows][64] with XOR chunk swizzle: LDS(row,c8) holds global chunk
// c8 ^ (row&7). Reader applies the same XOR -> conflict-free ds_read_b128.
template <int NI, int NT>
__device__ __forceinline__ void stage_swz(u16* lds, const u16* src, int tid) {
#pragma unroll
  for (int i = 0; i < NI; ++i) {
    const int idx = i * NT + tid;
    const int row = idx >> 3;
    const int c8 = (idx & 7) ^ (row & 7);
    async16(lds + idx * 8, src + (size_t)row * 256 + c8 * 8);
  }
}

// one K-tile of MFMA work from swizzled LDS buffers (A rows=128, B rows=cols)
__device__ __forceinline__ void compute_tile(const u16* ab, const u16* bb,
                                             f32x4 (&acc)[4][4], int wr, int wc,
                                             int l15, int l4, int sw) {
#pragma unroll
  for (int kk = 0; kk < 2; ++kk) {
    const int cs = ((kk * 4 + l4) ^ sw) * 8;
    bf16x8 af[4], bfr[4];
#pragma unroll
    for (int mi = 0; mi < 4; ++mi)
      af[mi] = *(const bf16x8*)&ab[(wr * 64 + mi * 16 + l15) * 64 + cs];
#pragma unroll
    for (int ni = 0; ni < 4; ++ni)
      bfr[ni] = *(const bf16x8*)&bb[(wc * 64 + ni * 16 + l15) * 64 + cs];
#pragma unroll
    for (int mi = 0; mi < 4; ++mi)
#pragma unroll
      for (int ni = 0; ni < 4; ++ni)
        acc[mi][ni] = __builtin_amdgcn_mfma_f32_16x16x32_bf16(af[mi], bfr[ni],
                                                              acc[mi][ni], 0, 0, 0);
  }
}

// ---------- prep: input transpose + 10 weight converts + stats zero ----------
__global__ void prep(const float* __restrict__ x1, const float* __restrict__ x2,
                     u16* __restrict__ X1, u16* __restrict__ X2,
                     const float* s0, const float* s1, const float* s2,
                     const float* s3, const float* s4, const float* s5,
                     const float* s6, const float* s7, const float* s8,
                     const float* s9, u16* __restrict__ wdst,
                     float* __restrict__ stats) {
  const int t = threadIdx.x;
  const int yy = blockIdx.y;
  if (yy >= 32) {
    const int m = yy - 32;
    if (m == 0 && blockIdx.x == 0) {
      ((float4*)stats)[t] = float4{0.f, 0.f, 0.f, 0.f};  // 1024 floats
    }
    const float* s;
    switch (m) {
      case 0: s = s0; break; case 1: s = s1; break; case 2: s = s2; break;
      case 3: s = s3; break; case 4: s = s4; break; case 5: s = s5; break;
      case 6: s = s6; break; case 7: s = s7; break; case 8: s = s8; break;
      default: s = s9; break;
    }
    const int i = (blockIdx.x * 256 + t) * 4;
    float4 v = *(const float4*)(s + i);
    uint2 o;
    o.x = pack2(v.x, v.y);
    o.y = pack2(v.z, v.w);
    *(uint2*)(wdst + (size_t)m * 65536 + i) = o;
    return;
  }
  __shared__ u16 tile[64][65];
  const int z = yy >> 2;
  const float* x = (z < 4) ? x1 : x2;
  u16* X = (z < 4) ? X1 : X2;
  const int b = z & 3, c0 = (yy & 3) * 64, hw0 = blockIdx.x * 64;
  {
    const int hw_l = t & 63, cb = t >> 6;
#pragma unroll
    for (int i = 0; i < 16; ++i) {
      const int c_l = cb * 16 + i;
      tile[c_l][hw_l] = f2b(x[((size_t)(b * 256 + c0 + c_l)) * 4096 + hw0 + hw_l]);
    }
  }
  __syncthreads();
  {
    const int c_l = t & 63, hb = t >> 6;
#pragma unroll
    for (int i = 0; i < 16; ++i) {
      const int hw_l = hb * 16 + i;
      X[((size_t)(b * 4096 + hw0 + hw_l)) * 256 + c0 + c_l] = tile[c_l][hw_l];
    }
  }
}

// ---------- QKV GEMM: 128x128 tile (proven structure) ----------
// grid (NPIX/128, 6, 2): y -> group g=y>>1, slab o0=(y&1)*128; z -> stream.
struct PG { const u16* X[6]; const u16* W[3]; u16* D[6]; };

__global__ void gemm_qkv(PG a) {
  __shared__ u16 As[2][8192];
  __shared__ u16 Bs[2][8192];
  const int tid = threadIdx.x;
  const int wave = tid >> 6, lane = tid & 63;
  const int p0 = blockIdx.x * 128;
  const int g = blockIdx.y >> 1, o0 = (blockIdx.y & 1) * 128;
  const int z = blockIdx.z;
  const u16* X = a.X[z * 3 + g];
  const u16* W = a.W[g];
  u16* D = a.D[z * 3 + g];
  const int wr = wave & 1, wc = wave >> 1;
  const int l15 = lane & 15, l4 = lane >> 4;
  const int sw = l15 & 7;
  f32x4 acc[4][4] = {};

  const u16* Xp = X + (size_t)p0 * 256;
  const u16* Wp = W + (size_t)o0 * 256;
  stage_swz<4, 256>(As[0], Xp, tid);
  stage_swz<4, 256>(Bs[0], Wp, tid);
  __syncthreads();

  for (int kt = 0; kt < 4; ++kt) {
    const int cur = kt & 1;
    if (kt < 3) {
      stage_swz<4, 256>(As[cur ^ 1], Xp + (kt + 1) * 64, tid);
      stage_swz<4, 256>(Bs[cur ^ 1], Wp + (kt + 1) * 64, tid);
    }
    compute_tile(As[cur], Bs[cur], acc, wr, wc, l15, l4, sw);
    __syncthreads();
  }
#pragma unroll
  for (int ni = 0; ni < 4; ++ni) {
    const int o = o0 + wc * 64 + ni * 16 + l15;
#pragma unroll
    for (int mi = 0; mi < 4; ++mi)
#pragma unroll
      for (int r = 0; r < 4; ++r) {
        const int p = p0 + wr * 64 + mi * 16 + l4 * 4 + r;
        D[(size_t)p * 256 + o] = f2b(acc[mi][ni][r]);
      }
  }
}

// ---------- fused: local 3x3 attn -> LDS A-tile -> fc GEMM + residual + LN ----
// grid (NPIX/128, 2), 512 threads, 68 KB LDS. Occupancy is work-limited
// (256 blocks = 1/CU), so the attn phase batch-issues all 9 neighbor loads
// per 8-ch chunk (9 outstanding dwordx4) to hide L2 latency with MLP.
struct Paf { const u16* Q[2]; const u16* K[2]; const u16* V[2];
             const u16* res[2]; u16* dst[2];
             const u16* W; const float* g; const float* b; };

__global__ __launch_bounds__(512) void attn_fc_ln(Paf a) {
  __shared__ u16 A4[2][8192];     // 32 KB: 2 swizzled [128][64] K-chunks
  __shared__ u16 Bs[16384];       // 32 KB: W tile [256][64], single-buffered
  __shared__ float red[2][128][4];
  const int tid = threadIdx.x;
  const int wave = tid >> 6, lane = tid & 63;
  const int wr = wave & 1, wc = wave >> 1;  // wc 0..3
  const int l15 = lane & 15, l4 = lane >> 4;
  const int sw = l15 & 7;
  const int p0 = blockIdx.x * 128;
  const int z = blockIdx.y;
  const u16* __restrict__ Q = a.Q[z];
  const u16* __restrict__ K = a.K[z];
  const u16* __restrict__ V = a.V[z];
  const u16* __restrict__ res = a.res[z];
  u16* dst = a.dst[z];

  const int p_l = tid >> 2, hh = tid & 3;   // pixel-in-tile, head-in-half
  const int p = p0 + p_l;
  const int yq = (p >> 6) & 63, xq = p & 63;

  // neighbor validity + offsets (uniform per thread across both halves)
  bool inb[9];
  ptrdiff_t noff[9];
#pragma unroll
  for (int j = 0; j < 9; ++j) {
    const int dy = j / 3 - 1, dx = j % 3 - 1;
    inb[j] = ((unsigned)(yq + dy) < 64u) && ((unsigned)(xq + dx) < 64u);
    noff[j] = (ptrdiff_t)(dy * 64 + dx) * 256;
  }

  // first W K-step DMA completes under the first attn phase
  stage_swz<4, 512>(Bs, a.W, tid);
  __builtin_amdgcn_sched_barrier(0);

  f32x4 acc[4][4] = {};
  for (int h = 0; h < 2; ++h) {
    // ---- attn for head = h*4 + hh (one unit per thread) ----
    const int head = h * 4 + hh;
    const size_t base = (size_t)p * 256 + head * 32;
    float q[32];
    {
      const uint4* qp = (const uint4*)(Q + base);
#pragma unroll
      for (int i = 0; i < 4; ++i) { uint4 w = qp[i]; unpack8(w, q + i * 8); }
    }
    // QK^T: batch-issue 9 neighbor loads per chunk, then unpack+dot.
    float accj[9];
#pragma unroll
    for (int j = 0; j < 9; ++j) accj[j] = 0.f;
#pragma unroll
    for (int i = 0; i < 4; ++i) {
      uint4 w[9];
#pragma unroll
      for (int j = 0; j < 9; ++j)
        if (inb[j]) w[j] = ((const uint4*)(K + base + noff[j]))[i];
#pragma unroll
      for (int j = 0; j < 9; ++j) {
        if (inb[j]) {
          float kf[8]; unpack8(w[j], kf);
#pragma unroll
          for (int d = 0; d < 8; ++d) accj[j] += q[i * 8 + d] * kf[d];
        }
      }
    }
    float lg[9];
    float mx = -1e30f;
#pragma unroll
    for (int j = 0; j < 9; ++j) {
      const float l = inb[j] ? accj[j] * 0.17677669529663687f : 0.f;  // 1/sqrt(32)
      lg[j] = l;
      mx = fmaxf(mx, l);
    }
    float pr[9], den = 0.f;
#pragma unroll
    for (int j = 0; j < 9; ++j) { pr[j] = __expf(lg[j] - mx); den += pr[j]; }
    // PV: same batched-load structure; per-chunk 8 accumulators.
    float out[32];
#pragma unroll
    for (int d = 0; d < 32; ++d) out[d] = 0.f;
#pragma unroll
    for (int i = 0; i < 4; ++i) {
      uint4 w[9];
#pragma unroll
      for (int j = 0; j < 9; ++j)
        if (inb[j]) w[j] = ((const uint4*)(V + base + noff[j]))[i];
#pragma unroll
      for (int j = 0; j < 9; ++j) {
        if (inb[j]) {
          float vf[8]; unpack8(w[j], vf);
          const float pw = pr[j];
#pragma unroll
          for (int d = 0; d < 8; ++d) out[i * 8 + d] += pw * vf[d];
        }
      }
    }
    const float inv = 1.f / den;
    // write 32 ch = 4 chunks into the two swizzled K-chunk tiles
#pragma unroll
    for (int i = 0; i < 4; ++i) {
      uint4 w;
      w.x = pack2(out[i * 8 + 0] * inv, out[i * 8 + 1] * inv);
      w.y = pack2(out[i * 8 + 2] * inv, out[i * 8 + 3] * inv);
      w.z = pack2(out[i * 8 + 4] * inv, out[i * 8 + 5] * inv);
      w.w = pack2(out[i * 8 + 6] * inv, out[i * 8 + 7] * inv);
      const int c8g = hh * 4 + i;            // 0..15 within half
      const int sub = c8g >> 3, c8in = c8g & 7;
      *(uint4*)&A4[sub][p_l * 64 + ((c8in ^ (p_l & 7)) * 8)] = w;
    }

    // ---- fc K-steps h*2 and h*2+1 ----
    __syncthreads();                                    // A4 + Bs ready
    compute_tile(A4[0], Bs, acc, wr, wc, l15, l4, sw);  // kt = h*2
    __syncthreads();                                    // Bs consumed
    stage_swz<4, 512>(Bs, a.W + (h * 2 + 1) * 64, tid);
    __syncthreads();                                    // Bs(kt+1) ready
    compute_tile(A4[1], Bs, acc, wr, wc, l15, l4, sw);  // kt = h*2+1
    __syncthreads();                                    // A4 + Bs free
    if (h == 0) {
      stage_swz<4, 512>(Bs, a.W + 2 * 64, tid);         // lands under attn h=1
      __builtin_amdgcn_sched_barrier(0);
    }
  }

  // ---- residual + per-pixel LN ----
#pragma unroll
  for (int mi = 0; mi < 4; ++mi) {
#pragma unroll
    for (int r = 0; r < 4; ++r) {
      const int pl = wr * 64 + mi * 16 + l4 * 4 + r;
      const int pp = p0 + pl;
      float s = 0.f, s2 = 0.f;
#pragma unroll
      for (int ni = 0; ni < 4; ++ni) {
        const int o = wc * 64 + ni * 16 + l15;
        float vv = acc[mi][ni][r] + b2f(res[(size_t)pp * 256 + o]);
        acc[mi][ni][r] = vv;
        s += vv; s2 += vv * vv;
      }
#pragma unroll
      for (int m = 1; m < 16; m <<= 1) {
        s += __shfl_xor(s, m); s2 += __shfl_xor(s2, m);
      }
      if (l15 == 0) { red[0][pl][wc] = s; red[1][pl][wc] = s2; }
    }
  }
  __syncthreads();

  float gv[4], bv[4];
#pragma unroll
  for (int ni = 0; ni < 4; ++ni) {
    const int o = wc * 64 + ni * 16 + l15;
    gv[ni] = a.g[o]; bv[ni] = a.b[o];
  }
#pragma unroll
  for (int mi = 0; mi < 4; ++mi) {
#pragma unroll
    for (int r = 0; r < 4; ++r) {
      const int pl = wr * 64 + mi * 16 + l4 * 4 + r;
      const float st = red[0][pl][0] + red[0][pl][1] + red[0][pl][2] + red[0][pl][3];
      const float s2t = red[1][pl][0] + red[1][pl][1] + red[1][pl][2] + red[1][pl][3];
      const float mu = st * (1.f / 256.f);
      const float var = s2t * (1.f / 256.f) - mu * mu;
      const float inv = rsqrtf(var + 1e-6f);
      const int pp = p0 + pl;
#pragma unroll
      for (int ni = 0; ni < 4; ++ni) {
        const int o = wc * 64 + ni * 16 + l15;
        dst[(size_t)pp * 256 + o] = f2b((acc[mi][ni][r] - mu) * inv * gv[ni] + bv[ni]);
      }
    }
  }
}

// ---------- fused FFN: mid = relu(X*W1+b1) in LDS; U = mid*W2+b2 + stats ----
// grid (NPIX/128, 2), 512 threads.
struct Pff { const u16* X[2]; u16* U[2]; float* st[2];
             const u16* W1; const float* b1; const u16* W2; const float* b2; };

__global__ __launch_bounds__(512) void ffn_fused(Pff a) {
  __shared__ u16 mid[4 * 8192];   // 64 KB: relu'd mid, 4 swizzled [128][64] chunks
  __shared__ u16 As[8192];        // 16 KB: X tile [128][64]
  __shared__ u16 Bs[16384];       // 32 KB: W tile [256][64]
  const int tid = threadIdx.x;
  const int wave = tid >> 6, lane = tid & 63;
  const int wr = wave & 1, wc = wave >> 1;  // wc 0..3
  const int l15 = lane & 15, l4 = lane >> 4;
  const int sw = l15 & 7;
  const int p0 = blockIdx.x * 128;
  const int z = blockIdx.y;
  const u16* X = a.X[z];
  u16* U = a.U[z];
  float* st = a.st[z];
  const u16* Xp = X + (size_t)p0 * 256;

  // ---- phase 1: mid = relu(X*W1 + b1), single-buffered A/B staging ----
  f32x4 acc1[4][4] = {};
  for (int kt = 0; kt < 4; ++kt) {
    stage_swz<2, 512>(As, Xp + kt * 64, tid);
    stage_swz<4, 512>(Bs, a.W1 + kt * 64, tid);
    __syncthreads();
    compute_tile(As, Bs, acc1, wr, wc, l15, l4, sw);
    __syncthreads();
  }
  // epilogue 1: bias + relu + bf16-round into swizzled mid chunks (kt = wc)
  {
    float bvv[4];
#pragma unroll
    for (int ni = 0; ni < 4; ++ni) bvv[ni] = a.b1[wc * 64 + ni * 16 + l15];
    u16* ml = mid + wc * 8192;
#pragma unroll
    for (int mi = 0; mi < 4; ++mi) {
#pragma unroll
      for (int r = 0; r < 4; ++r) {
        const int pl = wr * 64 + mi * 16 + l4 * 4 + r;
#pragma unroll
        for (int ni = 0; ni < 4; ++ni) {
          const int col = ni * 16 + l15;           // 0..63 within chunk
          const int c8 = col >> 3;
          const u16 hv = f2b(fmaxf(acc1[mi][ni][r] + bvv[ni], 0.f));
          ml[pl * 64 + ((c8 ^ (pl & 7)) * 8) + (col & 7)] = hv;
        }
      }
    }
  }

  // ---- phase 2: U = mid*W2 + b2, stats on bf16-rounded values ----
  f32x4 acc2[4][4] = {};
  for (int kt = 0; kt < 4; ++kt) {
    __syncthreads();           // kt=0: mid writes visible; else: Bs free
    stage_swz<4, 512>(Bs, a.W2 + kt * 64, tid);
    __syncthreads();
    compute_tile(mid + kt * 8192, Bs, acc2, wr, wc, l15, l4, sw);
  }
#pragma unroll
  for (int ni = 0; ni < 4; ++ni) {
    const int o = wc * 64 + ni * 16 + l15;
    const float bvv = a.b2[o];
    float s = 0.f, s2 = 0.f;
#pragma unroll
    for (int mi = 0; mi < 4; ++mi) {
#pragma unroll
      for (int r = 0; r < 4; ++r) {
        const int p = p0 + wr * 64 + mi * 16 + l4 * 4 + r;
        const u16 hv = f2b(acc2[mi][ni][r] + bvv);
        U[(size_t)p * 256 + o] = hv;
        const float vr = b2f(hv); s += vr; s2 += vr * vr;
      }
    }
    s += __shfl_xor(s, 16); s2 += __shfl_xor(s2, 16);
    s += __shfl_xor(s, 32); s2 += __shfl_xor(s2, 32);
    if (l4 == 0) { atomicAdd(&st[o], s); atomicAdd(&st[256 + o], s2); }
  }
}

// ---------- BN apply + residual + transpose back to fp32 [B,C,H,W] ----------
struct Pbn { const u16* U[2]; const u16* res[2]; const float* st[2];
             float* out[2]; const float* g; const float* b; };

__global__ void bn_apply(Pbn a) {
  __shared__ float tile[64][65];
  const int t = threadIdx.x;
  const int s = blockIdx.z >> 2, b = blockIdx.z & 3;
  const u16* __restrict__ U = a.U[s];
  const u16* __restrict__ res = a.res[s];
  const float* st = a.st[s];
  float* out = a.out[s];
  const int c0 = blockIdx.y * 64, hw0 = blockIdx.x * 64;
  {
    const int c_l = t & 63, hb = t >> 6;
    const int c = c0 + c_l;
    const float mu = st[c] * (1.f / 16384.f);
    const float var = st[256 + c] * (1.f / 16384.f) - mu * mu;
    const float sc = rsqrtf(var + 1e-5f) * a.g[c];
    const float sh = a.b[c] - mu * sc;
#pragma unroll
    for (int i = 0; i < 16; ++i) {
      const int hw_l = hb * 16 + i;
      const size_t p = (size_t)b * 4096 + hw0 + hw_l;
      const float u = b2f(U[p * 256 + c]);
      const float r = b2f(res[p * 256 + c]);
      tile[hw_l][c_l] = u * sc + sh + r;
    }
  }
  __syncthreads();
  {
    const int hw_l = t & 63, cb2 = t >> 6;
#pragma unroll
    for (int i = 0; i < 16; ++i) {
      const int c_l = cb2 * 16 + i;
      out[((size_t)(b * 256 + c0 + c_l)) * 4096 + hw0 + hw_l] = tile[hw_l][c_l];
    }
  }
}

extern "C" void kernel_launch(void* const* d_in, const int* in_sizes, int n_in,
                              void* d_out, int out_size, void* d_ws, size_t ws_size,
                              hipStream_t stream) {
  const float* input1 = (const float*)d_in[0];
  const float* input2 = (const float*)d_in[1];
  const float* slf_wq = (const float*)d_in[2];
  const float* slf_wk = (const float*)d_in[3];
  const float* slf_wv = (const float*)d_in[4];
  const float* slf_fc = (const float*)d_in[5];
  const float* slf_g  = (const float*)d_in[6];
  const float* slf_b  = (const float*)d_in[7];
  const float* crs_wq = (const float*)d_in[8];
  const float* crs_wk = (const float*)d_in[9];
  const float* crs_wv = (const float*)d_in[10];
  const float* crs_fc = (const float*)d_in[11];
  const float* crs_g  = (const float*)d_in[12];
  const float* crs_b  = (const float*)d_in[13];
  const float* ffn_w1 = (const float*)d_in[14];
  const float* ffn_b1 = (const float*)d_in[15];
  const float* ffn_w2 = (const float*)d_in[16];
  const float* ffn_b2 = (const float*)d_in[17];
  const float* bn_g   = (const float*)d_in[18];
  const float* bn_b   = (const float*)d_in[19];

  float* out = (float*)d_out;
  u16* ws = (u16*)d_ws;
  const size_t TS = (size_t)NPIX * CDIM;  // 4,194,304 elems = 8 MB bf16
  u16* b[10];
  for (int i = 0; i < 10; ++i) b[i] = ws + (size_t)i * TS;
  u16* wb = ws + 10 * TS;                 // 10 * 65536 bf16 weights
  u16 *Wsq = wb,             *Wsk = wb + 65536,     *Wsv = wb + 2 * 65536,
      *Wsf = wb + 3 * 65536, *Wcq = wb + 4 * 65536, *Wck = wb + 5 * 65536,
      *Wcv = wb + 6 * 65536, *Wcf = wb + 7 * 65536, *W1 = wb + 8 * 65536,
      *W2 = wb + 9 * 65536;
  float* stats = (float*)(wb + 10 * 65536);  // 2 x 512 floats

  const dim3 tb(256);

  prep<<<dim3(64, 42), tb, 0, stream>>>(input1, input2, b[0], b[1],
                                        slf_wq, slf_wk, slf_wv, slf_fc,
                                        crs_wq, crs_wk, crs_wv, crs_fc,
                                        ffn_w1, ffn_w2, wb, stats);

  // ---- self MHA ----
  PG sa;
  sa.X[0] = b[0]; sa.X[1] = b[0]; sa.X[2] = b[0];
  sa.X[3] = b[1]; sa.X[4] = b[1]; sa.X[5] = b[1];
  sa.W[0] = Wsq; sa.W[1] = Wsk; sa.W[2] = Wsv;
  sa.D[0] = b[4]; sa.D[1] = b[5]; sa.D[2] = b[6];
  sa.D[3] = b[7]; sa.D[4] = b[8]; sa.D[5] = b[9];
  gemm_qkv<<<dim3(NPIX / 128, 6, 2), tb, 0, stream>>>(sa);

  Paf f1;
  f1.Q[0] = b[4]; f1.K[0] = b[5]; f1.V[0] = b[6];
  f1.Q[1] = b[7]; f1.K[1] = b[8]; f1.V[1] = b[9];
  f1.res[0] = b[0]; f1.res[1] = b[1];
  f1.dst[0] = b[2]; f1.dst[1] = b[3];
  f1.W = Wsf; f1.g = slf_g; f1.b = slf_b;
  attn_fc_ln<<<dim3(NPIX / 128, 2), dim3(512), 0, stream>>>(f1);  // S1=b2, S2=b3

  // ---- cross MHA: C1 = mha(q=S1, kv=S2), C2 = mha(q=S2, kv=S1) ----
  PG ca;
  ca.X[0] = b[2]; ca.X[1] = b[3]; ca.X[2] = b[3];
  ca.X[3] = b[3]; ca.X[4] = b[2]; ca.X[5] = b[2];
  ca.W[0] = Wcq; ca.W[1] = Wck; ca.W[2] = Wcv;
  ca.D[0] = b[4]; ca.D[1] = b[5]; ca.D[2] = b[6];
  ca.D[3] = b[7]; ca.D[4] = b[8]; ca.D[5] = b[9];
  gemm_qkv<<<dim3(NPIX / 128, 6, 2), tb, 0, stream>>>(ca);

  Paf f2;
  f2.Q[0] = b[4]; f2.K[0] = b[5]; f2.V[0] = b[6];
  f2.Q[1] = b[7]; f2.K[1] = b[8]; f2.V[1] = b[9];
  f2.res[0] = b[2]; f2.res[1] = b[3];
  f2.dst[0] = b[0]; f2.dst[1] = b[1];
  f2.W = Wcf; f2.g = crs_g; f2.b = crs_b;
  attn_fc_ln<<<dim3(NPIX / 128, 2), dim3(512), 0, stream>>>(f2);  // C1=b0, C2=b1

  // ---- fused FFN (stats fused into W2 epilogue) ----
  Pff ff;
  ff.X[0] = b[0]; ff.X[1] = b[1];
  ff.U[0] = b[4]; ff.U[1] = b[7];
  ff.st[0] = stats; ff.st[1] = stats + 512;
  ff.W1 = W1; ff.b1 = ffn_b1; ff.W2 = W2; ff.b2 = ffn_b2;
  ffn_fused<<<dim3(NPIX / 128, 2), dim3(512), 0, stream>>>(ff);

  Pbn bn;
  bn.U[0] = b[4]; bn.U[1] = b[7];
  bn.res[0] = b[0]; bn.res[1] = b[1];
  bn.st[0] = stats; bn.st[1] = stats + 512;
  bn.out[0] = out; bn.out[1] = out + TS;
  bn.g = bn_g; bn.b = bn_b;
  bn_apply<<<dim3(64, 4, 8), tb, 0, stream>>>(bn);
}

// Round 10
// 282.993 us; speedup vs baseline: 1.0122x; 1.0122x over previous
//
#include <hip/hip_runtime.h>
#include <stdint.h>

using u16 = unsigned short;
typedef __bf16 bf16x8 __attribute__((ext_vector_type(8)));
typedef __bf16 bf16x2 __attribute__((ext_vector_type(2)));
typedef float f32x4 __attribute__((ext_vector_type(4)));

// B=4, C=256, H=W=64, NH=8, D=32, 3x3 window
#define NPIX 16384   // B*H*W
#define CDIM 256

__device__ __forceinline__ float b2f(u16 u) {
  union { unsigned i; float f; } c; c.i = ((unsigned)u) << 16; return c.f;
}
__device__ __forceinline__ u16 f2b(float x) {
  union { __bf16 h; u16 u; } c; c.h = (__bf16)x; return c.u;
}
__device__ __forceinline__ unsigned pack2(float a, float b) {
  union { bf16x2 v; unsigned u; } c; c.v[0] = (__bf16)a; c.v[1] = (__bf16)b; return c.u;
}
__device__ __forceinline__ void unpack8(uint4 w, float* f) {
  f[0] = b2f((u16)(w.x & 0xffffu)); f[1] = b2f((u16)(w.x >> 16));
  f[2] = b2f((u16)(w.y & 0xffffu)); f[3] = b2f((u16)(w.y >> 16));
  f[4] = b2f((u16)(w.z & 0xffffu)); f[5] = b2f((u16)(w.z >> 16));
  f[6] = b2f((u16)(w.w & 0xffffu)); f[7] = b2f((u16)(w.w >> 16));
}

// async global->LDS DMA, 16 B/lane.
__device__ __forceinline__ void async16(u16* l, const u16* g) {
  __builtin_amdgcn_global_load_lds((const __attribute__((address_space(1))) void*)g,
                                   (__attribute__((address_space(3))) void*)l, 16, 0, 0);
}

// Stage rows x 64ch (bf16) from row-major [*,256] source into linear LDS
// [rows][64] with XOR chunk swizzle: LDS(row,c8) holds global chunk
// c8 ^ (row&7). Reader applies the same XOR -> conflict-free ds_read_b128.
template <int NI, int NT>
__device__ __forceinline__ void stage_swz(u16* lds, const u16* src, int tid) {
#pragma unroll
  for (int i = 0; i < NI; ++i) {
    const int idx = i * NT + tid;
    const int row = idx >> 3;
    const int c8 = (idx & 7) ^ (row & 7);
    async16(lds + idx * 8, src + (size_t)row * 256 + c8 * 8);
  }
}

// one K-tile of MFMA work from swizzled LDS buffers (A rows, B rows=out-cols)
__device__ __forceinline__ void compute_tile(const u16* ab, const u16* bb,
                                             f32x4 (&acc)[4][4], int wr, int wc,
                                             int l15, int l4, int sw) {
#pragma unroll
  for (int kk = 0; kk < 2; ++kk) {
    const int cs = ((kk * 4 + l4) ^ sw) * 8;
    bf16x8 af[4], bfr[4];
#pragma unroll
    for (int mi = 0; mi < 4; ++mi)
      af[mi] = *(const bf16x8*)&ab[(wr * 64 + mi * 16 + l15) * 64 + cs];
#pragma unroll
    for (int ni = 0; ni < 4; ++ni)
      bfr[ni] = *(const bf16x8*)&bb[(wc * 64 + ni * 16 + l15) * 64 + cs];
#pragma unroll
    for (int mi = 0; mi < 4; ++mi)
#pragma unroll
      for (int ni = 0; ni < 4; ++ni)
        acc[mi][ni] = __builtin_amdgcn_mfma_f32_16x16x32_bf16(af[mi], bfr[ni],
                                                              acc[mi][ni], 0, 0, 0);
  }
}

// ---------- prep: input transpose + 10 weight converts + stats zero ----------
__global__ void prep(const float* __restrict__ x1, const float* __restrict__ x2,
                     u16* __restrict__ X1, u16* __restrict__ X2,
                     const float* s0, const float* s1, const float* s2,
                     const float* s3, const float* s4, const float* s5,
                     const float* s6, const float* s7, const float* s8,
                     const float* s9, u16* __restrict__ wdst,
                     float* __restrict__ stats) {
  const int t = threadIdx.x;
  const int yy = blockIdx.y;
  if (yy >= 32) {
    const int m = yy - 32;
    if (m == 0 && blockIdx.x == 0) {
      ((float4*)stats)[t] = float4{0.f, 0.f, 0.f, 0.f};  // 1024 floats
    }
    const float* s;
    switch (m) {
      case 0: s = s0; break; case 1: s = s1; break; case 2: s = s2; break;
      case 3: s = s3; break; case 4: s = s4; break; case 5: s = s5; break;
      case 6: s = s6; break; case 7: s = s7; break; case 8: s = s8; break;
      default: s = s9; break;
    }
    const int i = (blockIdx.x * 256 + t) * 4;
    float4 v = *(const float4*)(s + i);
    uint2 o;
    o.x = pack2(v.x, v.y);
    o.y = pack2(v.z, v.w);
    *(uint2*)(wdst + (size_t)m * 65536 + i) = o;
    return;
  }
  __shared__ u16 tile[64][65];
  const int z = yy >> 2;
  const float* x = (z < 4) ? x1 : x2;
  u16* X = (z < 4) ? X1 : X2;
  const int b = z & 3, c0 = (yy & 3) * 64, hw0 = blockIdx.x * 64;
  {
    const int hw_l = t & 63, cb = t >> 6;
#pragma unroll
    for (int i = 0; i < 16; ++i) {
      const int c_l = cb * 16 + i;
      tile[c_l][hw_l] = f2b(x[((size_t)(b * 256 + c0 + c_l)) * 4096 + hw0 + hw_l]);
    }
  }
  __syncthreads();
  {
    const int c_l = t & 63, hb = t >> 6;
#pragma unroll
    for (int i = 0; i < 16; ++i) {
      const int hw_l = hb * 16 + i;
      X[((size_t)(b * 4096 + hw0 + hw_l)) * 256 + c0 + c_l] = tile[c_l][hw_l];
    }
  }
}

// ---------- QKV GEMM: 128x128 tile ----------
// grid (NPIX/128, NG*2, 2): y -> group g=y>>1, slab o0=(y&1)*128; z -> stream.
struct PG { const u16* X[6]; const u16* W[3]; u16* D[6]; };

template <int NG>
__global__ void gemm_qkv(PG a) {
  __shared__ u16 As[2][8192];
  __shared__ u16 Bs[2][8192];
  const int tid = threadIdx.x;
  const int wave = tid >> 6, lane = tid & 63;
  const int p0 = blockIdx.x * 128;
  const int g = blockIdx.y >> 1, o0 = (blockIdx.y & 1) * 128;
  const int z = blockIdx.z;
  const u16* X = a.X[z * NG + g];
  const u16* W = a.W[g];
  u16* D = a.D[z * NG + g];
  const int wr = wave & 1, wc = wave >> 1;
  const int l15 = lane & 15, l4 = lane >> 4;
  const int sw = l15 & 7;
  f32x4 acc[4][4] = {};

  const u16* Xp = X + (size_t)p0 * 256;
  const u16* Wp = W + (size_t)o0 * 256;
  stage_swz<4, 256>(As[0], Xp, tid);
  stage_swz<4, 256>(Bs[0], Wp, tid);
  __syncthreads();

  for (int kt = 0; kt < 4; ++kt) {
    const int cur = kt & 1;
    if (kt < 3) {
      stage_swz<4, 256>(As[cur ^ 1], Xp + (kt + 1) * 64, tid);
      stage_swz<4, 256>(Bs[cur ^ 1], Wp + (kt + 1) * 64, tid);
    }
    compute_tile(As[cur], Bs[cur], acc, wr, wc, l15, l4, sw);
    __syncthreads();
  }
#pragma unroll
  for (int ni = 0; ni < 4; ++ni) {
    const int o = o0 + wc * 64 + ni * 16 + l15;
#pragma unroll
    for (int mi = 0; mi < 4; ++mi)
#pragma unroll
      for (int r = 0; r < 4; ++r) {
        const int p = p0 + wr * 64 + mi * 16 + l4 * 4 + r;
        D[(size_t)p * 256 + o] = f2b(acc[mi][ni][r]);
      }
  }
}

// ---------- attn_s: self attn -> fc+LN -> S (global+LDS) -> Qc = S*Wcq ----
// grid (NPIX/128, 2), 512 threads, 132 KB LDS.
struct Pas { const u16* Q[2]; const u16* K[2]; const u16* V[2];
             const u16* res[2]; u16* dstS[2]; u16* dstQc[2];
             const u16* Wfc; const u16* Wcq; const float* g; const float* b; };

__global__ __launch_bounds__(512) void attn_s(Pas a) {
  __shared__ u16 A4[2][8192];     // 32 KB: attn-out chunks / W dbuf slot
  __shared__ u16 Bs[16384];       // 32 KB: W tile
  __shared__ u16 S4[4][8192];     // 64 KB: S tile, 4 swizzled [128][64] chunks
  __shared__ float red[2][128][4];
  const int tid = threadIdx.x;
  const int wave = tid >> 6, lane = tid & 63;
  const int wr = wave & 1, wc = wave >> 1;
  const int l15 = lane & 15, l4 = lane >> 4;
  const int sw = l15 & 7;
  const int p0 = blockIdx.x * 128;
  const int z = blockIdx.y;
  const u16* __restrict__ Q = a.Q[z];
  const u16* __restrict__ K = a.K[z];
  const u16* __restrict__ V = a.V[z];
  const u16* __restrict__ res = a.res[z];
  u16* dstS = a.dstS[z];
  u16* dstQc = a.dstQc[z];

  const int p_l = tid >> 2, hh = tid & 3;
  const int p = p0 + p_l;
  const int yq = (p >> 6) & 63, xq = p & 63;

  bool inb[9];
  ptrdiff_t noff[9];
#pragma unroll
  for (int j = 0; j < 9; ++j) {
    const int dy = j / 3 - 1, dx = j % 3 - 1;
    inb[j] = ((unsigned)(yq + dy) < 64u) && ((unsigned)(xq + dx) < 64u);
    noff[j] = (ptrdiff_t)(dy * 64 + dx) * 256;
  }

  stage_swz<4, 512>(Bs, a.Wfc, tid);
  __builtin_amdgcn_sched_barrier(0);

  f32x4 acc[4][4] = {};
  for (int h = 0; h < 2; ++h) {
    const int head = h * 4 + hh;
    const size_t base = (size_t)p * 256 + head * 32;
    float q[32];
    {
      const uint4* qp = (const uint4*)(Q + base);
#pragma unroll
      for (int i = 0; i < 4; ++i) { uint4 w = qp[i]; unpack8(w, q + i * 8); }
    }
    float accj[9];
#pragma unroll
    for (int j = 0; j < 9; ++j) accj[j] = 0.f;
#pragma unroll
    for (int i = 0; i < 4; ++i) {
      uint4 w[9];
#pragma unroll
      for (int j = 0; j < 9; ++j)
        if (inb[j]) w[j] = ((const uint4*)(K + base + noff[j]))[i];
#pragma unroll
      for (int j = 0; j < 9; ++j) {
        if (inb[j]) {
          float kf[8]; unpack8(w[j], kf);
#pragma unroll
          for (int d = 0; d < 8; ++d) accj[j] += q[i * 8 + d] * kf[d];
        }
      }
    }
    float lg[9];
    float mx = -1e30f;
#pragma unroll
    for (int j = 0; j < 9; ++j) {
      const float l = inb[j] ? accj[j] * 0.17677669529663687f : 0.f;
      lg[j] = l;
      mx = fmaxf(mx, l);
    }
    float pr[9], den = 0.f;
#pragma unroll
    for (int j = 0; j < 9; ++j) { pr[j] = __expf(lg[j] - mx); den += pr[j]; }
    float out[32];
#pragma unroll
    for (int d = 0; d < 32; ++d) out[d] = 0.f;
#pragma unroll
    for (int i = 0; i < 4; ++i) {
      uint4 w[9];
#pragma unroll
      for (int j = 0; j < 9; ++j)
        if (inb[j]) w[j] = ((const uint4*)(V + base + noff[j]))[i];
#pragma unroll
      for (int j = 0; j < 9; ++j) {
        if (inb[j]) {
          float vf[8]; unpack8(w[j], vf);
          const float pw = pr[j];
#pragma unroll
          for (int d = 0; d < 8; ++d) out[i * 8 + d] += pw * vf[d];
        }
      }
    }
    const float inv = 1.f / den;
#pragma unroll
    for (int i = 0; i < 4; ++i) {
      uint4 w;
      w.x = pack2(out[i * 8 + 0] * inv, out[i * 8 + 1] * inv);
      w.y = pack2(out[i * 8 + 2] * inv, out[i * 8 + 3] * inv);
      w.z = pack2(out[i * 8 + 4] * inv, out[i * 8 + 5] * inv);
      w.w = pack2(out[i * 8 + 6] * inv, out[i * 8 + 7] * inv);
      const int c8g = hh * 4 + i;
      const int sub = c8g >> 3, c8in = c8g & 7;
      *(uint4*)&A4[sub][p_l * 64 + ((c8in ^ (p_l & 7)) * 8)] = w;
    }

    __syncthreads();
    compute_tile(A4[0], Bs, acc, wr, wc, l15, l4, sw);
    __syncthreads();
    stage_swz<4, 512>(Bs, a.Wfc + (h * 2 + 1) * 64, tid);
    __syncthreads();
    compute_tile(A4[1], Bs, acc, wr, wc, l15, l4, sw);
    __syncthreads();
    if (h == 0) {
      stage_swz<4, 512>(Bs, a.Wfc + 2 * 64, tid);
      __builtin_amdgcn_sched_barrier(0);
    }
  }

  // stage Wcq k0 under the LN epilogue (Bs free now)
  stage_swz<4, 512>(Bs, a.Wcq, tid);
  __builtin_amdgcn_sched_barrier(0);

  // residual + per-pixel LN -> dstS global + S4 LDS
#pragma unroll
  for (int mi = 0; mi < 4; ++mi) {
#pragma unroll
    for (int r = 0; r < 4; ++r) {
      const int pl = wr * 64 + mi * 16 + l4 * 4 + r;
      const int pp = p0 + pl;
      float s = 0.f, s2 = 0.f;
#pragma unroll
      for (int ni = 0; ni < 4; ++ni) {
        const int o = wc * 64 + ni * 16 + l15;
        float vv = acc[mi][ni][r] + b2f(res[(size_t)pp * 256 + o]);
        acc[mi][ni][r] = vv;
        s += vv; s2 += vv * vv;
      }
#pragma unroll
      for (int m = 1; m < 16; m <<= 1) {
        s += __shfl_xor(s, m); s2 += __shfl_xor(s2, m);
      }
      if (l15 == 0) { red[0][pl][wc] = s; red[1][pl][wc] = s2; }
    }
  }
  __syncthreads();

  float gv[4], bv[4];
#pragma unroll
  for (int ni = 0; ni < 4; ++ni) {
    const int o = wc * 64 + ni * 16 + l15;
    gv[ni] = a.g[o]; bv[ni] = a.b[o];
  }
#pragma unroll
  for (int mi = 0; mi < 4; ++mi) {
#pragma unroll
    for (int r = 0; r < 4; ++r) {
      const int pl = wr * 64 + mi * 16 + l4 * 4 + r;
      const float st = red[0][pl][0] + red[0][pl][1] + red[0][pl][2] + red[0][pl][3];
      const float s2t = red[1][pl][0] + red[1][pl][1] + red[1][pl][2] + red[1][pl][3];
      const float mu = st * (1.f / 256.f);
      const float var = s2t * (1.f / 256.f) - mu * mu;
      const float inv = rsqrtf(var + 1e-6f);
      const int pp = p0 + pl;
#pragma unroll
      for (int ni = 0; ni < 4; ++ni) {
        const int o = wc * 64 + ni * 16 + l15;
        const u16 hv = f2b((acc[mi][ni][r] - mu) * inv * gv[ni] + bv[ni]);
        dstS[(size_t)pp * 256 + o] = hv;
        const int c8 = (ni * 16 + l15) >> 3;
        S4[wc][pl * 64 + ((c8 ^ (pl & 7)) * 8) + (l15 & 7)] = hv;
      }
    }
  }
  __syncthreads();   // S4 complete; Wcq k0 loaded (barrier drains vmcnt)

  // Qc = S * Wcq, W dbuf between Bs and A4
  u16* a4f = &A4[0][0];
  f32x4 accq[4][4] = {};
  for (int kt = 0; kt < 4; ++kt) {
    if (kt < 3)
      stage_swz<4, 512>(((kt + 1) & 1) ? a4f : Bs, a.Wcq + (kt + 1) * 64, tid);
    compute_tile(&S4[kt][0], (kt & 1) ? a4f : Bs, accq, wr, wc, l15, l4, sw);
    __syncthreads();
  }
#pragma unroll
  for (int ni = 0; ni < 4; ++ni) {
    const int o = wc * 64 + ni * 16 + l15;
#pragma unroll
    for (int mi = 0; mi < 4; ++mi)
#pragma unroll
      for (int r = 0; r < 4; ++r) {
        const int pp = p0 + wr * 64 + mi * 16 + l4 * 4 + r;
        dstQc[(size_t)pp * 256 + o] = f2b(accq[mi][ni][r]);
      }
  }
}

// ---------- attn_c_ffn: cross attn -> fc+LN -> C -> FFN -> U + stats ------
// grid (NPIX/128, 2), 512 threads, 132 KB LDS.
struct Pcf { const u16* Q[2]; const u16* K[2]; const u16* V[2];
             const u16* resS[2]; u16* dstC[2]; u16* U[2]; float* st[2];
             const u16* Wfc; const float* g; const float* b;
             const u16* W1; const float* bb1; const u16* W2; const float* bb2; };

__global__ __launch_bounds__(512) void attn_c_ffn(Pcf a) {
  __shared__ u16 A4[2][8192];     // 32 KB
  __shared__ u16 Bs[16384];       // 32 KB
  __shared__ u16 M4[4][8192];     // 64 KB: C tile, then relu'd mid
  __shared__ float red[2][128][4];
  const int tid = threadIdx.x;
  const int wave = tid >> 6, lane = tid & 63;
  const int wr = wave & 1, wc = wave >> 1;
  const int l15 = lane & 15, l4 = lane >> 4;
  const int sw = l15 & 7;
  const int p0 = blockIdx.x * 128;
  const int z = blockIdx.y;
  const u16* __restrict__ Q = a.Q[z];
  const u16* __restrict__ K = a.K[z];
  const u16* __restrict__ V = a.V[z];
  const u16* __restrict__ resS = a.resS[z];
  u16* dstC = a.dstC[z];
  u16* U = a.U[z];
  float* st = a.st[z];

  const int p_l = tid >> 2, hh = tid & 3;
  const int p = p0 + p_l;
  const int yq = (p >> 6) & 63, xq = p & 63;

  bool inb[9];
  ptrdiff_t noff[9];
#pragma unroll
  for (int j = 0; j < 9; ++j) {
    const int dy = j / 3 - 1, dx = j % 3 - 1;
    inb[j] = ((unsigned)(yq + dy) < 64u) && ((unsigned)(xq + dx) < 64u);
    noff[j] = (ptrdiff_t)(dy * 64 + dx) * 256;
  }

  stage_swz<4, 512>(Bs, a.Wfc, tid);
  __builtin_amdgcn_sched_barrier(0);

  f32x4 acc[4][4] = {};
  for (int h = 0; h < 2; ++h) {
    const int head = h * 4 + hh;
    const size_t base = (size_t)p * 256 + head * 32;
    float q[32];
    {
      const uint4* qp = (const uint4*)(Q + base);
#pragma unroll
      for (int i = 0; i < 4; ++i) { uint4 w = qp[i]; unpack8(w, q + i * 8); }
    }
    float accj[9];
#pragma unroll
    for (int j = 0; j < 9; ++j) accj[j] = 0.f;
#pragma unroll
    for (int i = 0; i < 4; ++i) {
      uint4 w[9];
#pragma unroll
      for (int j = 0; j < 9; ++j)
        if (inb[j]) w[j] = ((const uint4*)(K + base + noff[j]))[i];
#pragma unroll
      for (int j = 0; j < 9; ++j) {
        if (inb[j]) {
          float kf[8]; unpack8(w[j], kf);
#pragma unroll
          for (int d = 0; d < 8; ++d) accj[j] += q[i * 8 + d] * kf[d];
        }
      }
    }
    float lg[9];
    float mx = -1e30f;
#pragma unroll
    for (int j = 0; j < 9; ++j) {
      const float l = inb[j] ? accj[j] * 0.17677669529663687f : 0.f;
      lg[j] = l;
      mx = fmaxf(mx, l);
    }
    float pr[9], den = 0.f;
#pragma unroll
    for (int j = 0; j < 9; ++j) { pr[j] = __expf(lg[j] - mx); den += pr[j]; }
    float out[32];
#pragma unroll
    for (int d = 0; d < 32; ++d) out[d] = 0.f;
#pragma unroll
    for (int i = 0; i < 4; ++i) {
      uint4 w[9];
#pragma unroll
      for (int j = 0; j < 9; ++j)
        if (inb[j]) w[j] = ((const uint4*)(V + base + noff[j]))[i];
#pragma unroll
      for (int j = 0; j < 9; ++j) {
        if (inb[j]) {
          float vf[8]; unpack8(w[j], vf);
          const float pw = pr[j];
#pragma unroll
          for (int d = 0; d < 8; ++d) out[i * 8 + d] += pw * vf[d];
        }
      }
    }
    const float inv = 1.f / den;
#pragma unroll
    for (int i = 0; i < 4; ++i) {
      uint4 w;
      w.x = pack2(out[i * 8 + 0] * inv, out[i * 8 + 1] * inv);
      w.y = pack2(out[i * 8 + 2] * inv, out[i * 8 + 3] * inv);
      w.z = pack2(out[i * 8 + 4] * inv, out[i * 8 + 5] * inv);
      w.w = pack2(out[i * 8 + 6] * inv, out[i * 8 + 7] * inv);
      const int c8g = hh * 4 + i;
      const int sub = c8g >> 3, c8in = c8g & 7;
      *(uint4*)&A4[sub][p_l * 64 + ((c8in ^ (p_l & 7)) * 8)] = w;
    }

    __syncthreads();
    compute_tile(A4[0], Bs, acc, wr, wc, l15, l4, sw);
    __syncthreads();
    stage_swz<4, 512>(Bs, a.Wfc + (h * 2 + 1) * 64, tid);
    __syncthreads();
    compute_tile(A4[1], Bs, acc, wr, wc, l15, l4, sw);
    __syncthreads();
    if (h == 0) {
      stage_swz<4, 512>(Bs, a.Wfc + 2 * 64, tid);
      __builtin_amdgcn_sched_barrier(0);
    }
  }

  // stage W1 k0 under the LN epilogue
  stage_swz<4, 512>(Bs, a.W1, tid);
  __builtin_amdgcn_sched_barrier(0);

  // residual + LN -> dstC global + M4 LDS
#pragma unroll
  for (int mi = 0; mi < 4; ++mi) {
#pragma unroll
    for (int r = 0; r < 4; ++r) {
      const int pl = wr * 64 + mi * 16 + l4 * 4 + r;
      const int pp = p0 + pl;
      float s = 0.f, s2 = 0.f;
#pragma unroll
      for (int ni = 0; ni < 4; ++ni) {
        const int o = wc * 64 + ni * 16 + l15;
        float vv = acc[mi][ni][r] + b2f(resS[(size_t)pp * 256 + o]);
        acc[mi][ni][r] = vv;
        s += vv; s2 += vv * vv;
      }
#pragma unroll
      for (int m = 1; m < 16; m <<= 1) {
        s += __shfl_xor(s, m); s2 += __shfl_xor(s2, m);
      }
      if (l15 == 0) { red[0][pl][wc] = s; red[1][pl][wc] = s2; }
    }
  }
  __syncthreads();

  float gv[4], bv[4];
#pragma unroll
  for (int ni = 0; ni < 4; ++ni) {
    const int o = wc * 64 + ni * 16 + l15;
    gv[ni] = a.g[o]; bv[ni] = a.b[o];
  }
#pragma unroll
  for (int mi = 0; mi < 4; ++mi) {
#pragma unroll
    for (int r = 0; r < 4; ++r) {
      const int pl = wr * 64 + mi * 16 + l4 * 4 + r;
      const float st2 = red[0][pl][0] + red[0][pl][1] + red[0][pl][2] + red[0][pl][3];
      const float s2t = red[1][pl][0] + red[1][pl][1] + red[1][pl][2] + red[1][pl][3];
      const float mu = st2 * (1.f / 256.f);
      const float var = s2t * (1.f / 256.f) - mu * mu;
      const float inv = rsqrtf(var + 1e-6f);
      const int pp = p0 + pl;
#pragma unroll
      for (int ni = 0; ni < 4; ++ni) {
        const int o = wc * 64 + ni * 16 + l15;
        const u16 hv = f2b((acc[mi][ni][r] - mu) * inv * gv[ni] + bv[ni]);
        dstC[(size_t)pp * 256 + o] = hv;
        const int c8 = (ni * 16 + l15) >> 3;
        M4[wc][pl * 64 + ((c8 ^ (pl & 7)) * 8) + (l15 & 7)] = hv;
      }
    }
  }
  __syncthreads();   // M4(C) complete; W1 k0 loaded

  u16* a4f = &A4[0][0];
  // ffn1: acc1 = C*W1
  f32x4 acc1[4][4] = {};
  for (int kt = 0; kt < 4; ++kt) {
    if (kt < 3)
      stage_swz<4, 512>(((kt + 1) & 1) ? a4f : Bs, a.W1 + (kt + 1) * 64, tid);
    compute_tile(&M4[kt][0], (kt & 1) ? a4f : Bs, acc1, wr, wc, l15, l4, sw);
    __syncthreads();
  }
  // stage W2 k0 under mid epilogue (Bs free: last compute used A4)
  stage_swz<4, 512>(Bs, a.W2, tid);
  __builtin_amdgcn_sched_barrier(0);
  // mid = relu(acc1 + b1) -> overwrite M4 (chunk wc)
  {
    float bvv[4];
#pragma unroll
    for (int ni = 0; ni < 4; ++ni) bvv[ni] = a.bb1[wc * 64 + ni * 16 + l15];
    u16* ml = &M4[wc][0];
#pragma unroll
    for (int mi = 0; mi < 4; ++mi) {
#pragma unroll
      for (int r = 0; r < 4; ++r) {
        const int pl = wr * 64 + mi * 16 + l4 * 4 + r;
#pragma unroll
        for (int ni = 0; ni < 4; ++ni) {
          const int col = ni * 16 + l15;
          const int c8 = col >> 3;
          const u16 hv = f2b(fmaxf(acc1[mi][ni][r] + bvv[ni], 0.f));
          ml[pl * 64 + ((c8 ^ (pl & 7)) * 8) + (col & 7)] = hv;
        }
      }
    }
  }
  __syncthreads();   // mid visible; W2 k0 loaded

  // ffn2: U = mid*W2 + b2, stats on bf16-rounded values
  f32x4 acc2[4][4] = {};
  for (int kt = 0; kt < 4; ++kt) {
    if (kt < 3)
      stage_swz<4, 512>(((kt + 1) & 1) ? a4f : Bs, a.W2 + (kt + 1) * 64, tid);
    compute_tile(&M4[kt][0], (kt & 1) ? a4f : Bs, acc2, wr, wc, l15, l4, sw);
    __syncthreads();
  }
#pragma unroll
  for (int ni = 0; ni < 4; ++ni) {
    const int o = wc * 64 + ni * 16 + l15;
    const float bvv = a.bb2[o];
    float s = 0.f, s2 = 0.f;
#pragma unroll
    for (int mi = 0; mi < 4; ++mi) {
#pragma unroll
      for (int r = 0; r < 4; ++r) {
        const int pp = p0 + wr * 64 + mi * 16 + l4 * 4 + r;
        const u16 hv = f2b(acc2[mi][ni][r] + bvv);
        U[(size_t)pp * 256 + o] = hv;
        const float vr = b2f(hv); s += vr; s2 += vr * vr;
      }
    }
    s += __shfl_xor(s, 16); s2 += __shfl_xor(s2, 16);
    s += __shfl_xor(s, 32); s2 += __shfl_xor(s2, 32);
    if (l4 == 0) { atomicAdd(&st[o], s); atomicAdd(&st[256 + o], s2); }
  }
}

// ---------- BN apply + residual + transpose back to fp32 [B,C,H,W] ----------
struct Pbn { const u16* U[2]; const u16* res[2]; const float* st[2];
             float* out[2]; const float* g; const float* b; };

__global__ void bn_apply(Pbn a) {
  __shared__ float tile[64][65];
  const int t = threadIdx.x;
  const int s = blockIdx.z >> 2, b = blockIdx.z & 3;
  const u16* __restrict__ U = a.U[s];
  const u16* __restrict__ res = a.res[s];
  const float* st = a.st[s];
  float* out = a.out[s];
  const int c0 = blockIdx.y * 64, hw0 = blockIdx.x * 64;
  {
    const int c_l = t & 63, hb = t >> 6;
    const int c = c0 + c_l;
    const float mu = st[c] * (1.f / 16384.f);
    const float var = st[256 + c] * (1.f / 16384.f) - mu * mu;
    const float sc = rsqrtf(var + 1e-5f) * a.g[c];
    const float sh = a.b[c] - mu * sc;
#pragma unroll
    for (int i = 0; i < 16; ++i) {
      const int hw_l = hb * 16 + i;
      const size_t p = (size_t)b * 4096 + hw0 + hw_l;
      const float u = b2f(U[p * 256 + c]);
      const float r = b2f(res[p * 256 + c]);
      tile[hw_l][c_l] = u * sc + sh + r;
    }
  }
  __syncthreads();
  {
    const int hw_l = t & 63, cb2 = t >> 6;
#pragma unroll
    for (int i = 0; i < 16; ++i) {
      const int c_l = cb2 * 16 + i;
      out[((size_t)(b * 256 + c0 + c_l)) * 4096 + hw0 + hw_l] = tile[hw_l][c_l];
    }
  }
}

extern "C" void kernel_launch(void* const* d_in, const int* in_sizes, int n_in,
                              void* d_out, int out_size, void* d_ws, size_t ws_size,
                              hipStream_t stream) {
  const float* input1 = (const float*)d_in[0];
  const float* input2 = (const float*)d_in[1];
  const float* slf_wq = (const float*)d_in[2];
  const float* slf_wk = (const float*)d_in[3];
  const float* slf_wv = (const float*)d_in[4];
  const float* slf_fc = (const float*)d_in[5];
  const float* slf_g  = (const float*)d_in[6];
  const float* slf_b  = (const float*)d_in[7];
  const float* crs_wq = (const float*)d_in[8];
  const float* crs_wk = (const float*)d_in[9];
  const float* crs_wv = (const float*)d_in[10];
  const float* crs_fc = (const float*)d_in[11];
  const float* crs_g  = (const float*)d_in[12];
  const float* crs_b  = (const float*)d_in[13];
  const float* ffn_w1 = (const float*)d_in[14];
  const float* ffn_b1 = (const float*)d_in[15];
  const float* ffn_w2 = (const float*)d_in[16];
  const float* ffn_b2 = (const float*)d_in[17];
  const float* bn_g   = (const float*)d_in[18];
  const float* bn_b   = (const float*)d_in[19];

  float* out = (float*)d_out;
  u16* ws = (u16*)d_ws;
  const size_t TS = (size_t)NPIX * CDIM;  // 8 MB bf16
  u16* b[10];
  for (int i = 0; i < 10; ++i) b[i] = ws + (size_t)i * TS;
  u16* wb = ws + 10 * TS;                 // 10 * 65536 bf16 weights
  u16 *Wsq = wb,             *Wsk = wb + 65536,     *Wsv = wb + 2 * 65536,
      *Wsf = wb + 3 * 65536, *Wcq = wb + 4 * 65536, *Wck = wb + 5 * 65536,
      *Wcv = wb + 6 * 65536, *Wcf = wb + 7 * 65536, *W1 = wb + 8 * 65536,
      *W2 = wb + 9 * 65536;
  float* stats = (float*)(wb + 10 * 65536);  // 2 x 512 floats

  const dim3 tb(256);

  prep<<<dim3(64, 42), tb, 0, stream>>>(input1, input2, b[0], b[1],
                                        slf_wq, slf_wk, slf_wv, slf_fc,
                                        crs_wq, crs_wk, crs_wv, crs_fc,
                                        ffn_w1, ffn_w2, wb, stats);

  // ---- self QKV ----
  PG sa;
  sa.X[0] = b[0]; sa.X[1] = b[0]; sa.X[2] = b[0];
  sa.X[3] = b[1]; sa.X[4] = b[1]; sa.X[5] = b[1];
  sa.W[0] = Wsq; sa.W[1] = Wsk; sa.W[2] = Wsv;
  sa.D[0] = b[4]; sa.D[1] = b[5]; sa.D[2] = b[6];
  sa.D[3] = b[7]; sa.D[4] = b[8]; sa.D[5] = b[9];
  gemm_qkv<3><<<dim3(NPIX / 128, 6, 2), tb, 0, stream>>>(sa);

  // ---- self attn + fc/LN -> S, + cross-Q ----
  Pas f1;
  f1.Q[0] = b[4]; f1.K[0] = b[5]; f1.V[0] = b[6];
  f1.Q[1] = b[7]; f1.K[1] = b[8]; f1.V[1] = b[9];
  f1.res[0] = b[0]; f1.res[1] = b[1];
  f1.dstS[0] = b[2]; f1.dstS[1] = b[3];
  f1.dstQc[0] = b[4]; f1.dstQc[1] = b[7];   // row-local overwrite of self-Q
  f1.Wfc = Wsf; f1.Wcq = Wcq; f1.g = slf_g; f1.b = slf_b;
  attn_s<<<dim3(NPIX / 128, 2), dim3(512), 0, stream>>>(f1);

  // ---- cross K/V only ----
  PG ca;
  ca.X[0] = b[2]; ca.X[1] = b[2];   // z=0: S1 -> Kc0, Vc0
  ca.X[2] = b[3]; ca.X[3] = b[3];   // z=1: S2 -> Kc1, Vc1
  ca.X[4] = nullptr; ca.X[5] = nullptr;
  ca.W[0] = Wck; ca.W[1] = Wcv; ca.W[2] = nullptr;
  ca.D[0] = b[5]; ca.D[1] = b[6];   // Kc0, Vc0
  ca.D[2] = b[8]; ca.D[3] = b[9];   // Kc1, Vc1
  ca.D[4] = nullptr; ca.D[5] = nullptr;
  gemm_qkv<2><<<dim3(NPIX / 128, 4, 2), tb, 0, stream>>>(ca);

  // ---- cross attn + fc/LN -> C, + FFN -> U + stats ----
  Pcf f2;
  f2.Q[0] = b[4]; f2.K[0] = b[8]; f2.V[0] = b[9];   // C1 = mha(q=S1, kv=S2)
  f2.Q[1] = b[7]; f2.K[1] = b[5]; f2.V[1] = b[6];   // C2 = mha(q=S2, kv=S1)
  f2.resS[0] = b[2]; f2.resS[1] = b[3];
  f2.dstC[0] = b[0]; f2.dstC[1] = b[1];
  f2.U[0] = b[2]; f2.U[1] = b[3];                   // row-local overwrite of S
  f2.st[0] = stats; f2.st[1] = stats + 512;
  f2.Wfc = Wcf; f2.g = crs_g; f2.b = crs_b;
  f2.W1 = W1; f2.bb1 = ffn_b1; f2.W2 = W2; f2.bb2 = ffn_b2;
  attn_c_ffn<<<dim3(NPIX / 128, 2), dim3(512), 0, stream>>>(f2);

  Pbn bn;
  bn.U[0] = b[2]; bn.U[1] = b[3];
  bn.res[0] = b[0]; bn.res[1] = b[1];
  bn.st[0] = stats; bn.st[1] = stats + 512;
  bn.out[0] = out; bn.out[1] = out + TS;
  bn.g = bn_g; bn.b = bn_b;
  bn_apply<<<dim3(64, 4, 8), tb, 0, stream>>>(bn);
}

// Round 11
// 274.605 us; speedup vs baseline: 1.0431x; 1.0305x over previous
//
#include <hip/hip_runtime.h>
#include <stdint.h>

using u16 = unsigned short;
typedef __bf16 bf16x8 __attribute__((ext_vector_type(8)));
typedef __bf16 bf16x2 __attribute__((ext_vector_type(2)));
typedef float f32x4 __attribute__((ext_vector_type(4)));

// B=4, C=256, H=W=64, NH=8, D=32, 3x3 window
#define NPIX 16384   // B*H*W
#define CDIM 256

__device__ __forceinline__ float b2f(u16 u) {
  union { unsigned i; float f; } c; c.i = ((unsigned)u) << 16; return c.f;
}
__device__ __forceinline__ u16 f2b(float x) {
  union { __bf16 h; u16 u; } c; c.h = (__bf16)x; return c.u;
}
__device__ __forceinline__ unsigned pack2(float a, float b) {
  union { bf16x2 v; unsigned u; } c; c.v[0] = (__bf16)a; c.v[1] = (__bf16)b; return c.u;
}
__device__ __forceinline__ void unpack8(uint4 w, float* f) {
  f[0] = b2f((u16)(w.x & 0xffffu)); f[1] = b2f((u16)(w.x >> 16));
  f[2] = b2f((u16)(w.y & 0xffffu)); f[3] = b2f((u16)(w.y >> 16));
  f[4] = b2f((u16)(w.z & 0xffffu)); f[5] = b2f((u16)(w.z >> 16));
  f[6] = b2f((u16)(w.w & 0xffffu)); f[7] = b2f((u16)(w.w >> 16));
}

// async global->LDS DMA, 16 B/lane.
__device__ __forceinline__ void async16(u16* l, const u16* g) {
  __builtin_amdgcn_global_load_lds((const __attribute__((address_space(1))) void*)g,
                                   (__attribute__((address_space(3))) void*)l, 16, 0, 0);
}

// Stage rows x 64ch (bf16) from row-major [*,256] source into linear LDS
// [rows][64] with XOR chunk swizzle: LDS(row,c8) holds global chunk
// c8 ^ (row&7). Reader applies the same XOR -> conflict-free ds_read_b128.
template <int NI, int NT>
__device__ __forceinline__ void stage_swz(u16* lds, const u16* src, int tid) {
#pragma unroll
  for (int i = 0; i < NI; ++i) {
    const int idx = i * NT + tid;
    const int row = idx >> 3;
    const int c8 = (idx & 7) ^ (row & 7);
    async16(lds + idx * 8, src + (size_t)row * 256 + c8 * 8);
  }
}

// one K-tile of MFMA work from swizzled LDS buffers (A rows, B rows=out-cols)
__device__ __forceinline__ void compute_tile(const u16* ab, const u16* bb,
                                             f32x4 (&acc)[4][4], int wr, int wc,
                                             int l15, int l4, int sw) {
#pragma unroll
  for (int kk = 0; kk < 2; ++kk) {
    const int cs = ((kk * 4 + l4) ^ sw) * 8;
    bf16x8 af[4], bfr[4];
#pragma unroll
    for (int mi = 0; mi < 4; ++mi)
      af[mi] = *(const bf16x8*)&ab[(wr * 64 + mi * 16 + l15) * 64 + cs];
#pragma unroll
    for (int ni = 0; ni < 4; ++ni)
      bfr[ni] = *(const bf16x8*)&bb[(wc * 64 + ni * 16 + l15) * 64 + cs];
#pragma unroll
    for (int mi = 0; mi < 4; ++mi)
#pragma unroll
      for (int ni = 0; ni < 4; ++ni)
        acc[mi][ni] = __builtin_amdgcn_mfma_f32_16x16x32_bf16(af[mi], bfr[ni],
                                                              acc[mi][ni], 0, 0, 0);
  }
}

// ---------- prep: input transpose + 10 weight converts + stats zero ----------
__global__ void prep(const float* __restrict__ x1, const float* __restrict__ x2,
                     u16* __restrict__ X1, u16* __restrict__ X2,
                     const float* s0, const float* s1, const float* s2,
                     const float* s3, const float* s4, const float* s5,
                     const float* s6, const float* s7, const float* s8,
                     const float* s9, u16* __restrict__ wdst,
                     float* __restrict__ stats) {
  const int t = threadIdx.x;
  const int yy = blockIdx.y;
  if (yy >= 32) {
    const int m = yy - 32;
    if (m == 0 && blockIdx.x == 0) {
      ((float4*)stats)[t] = float4{0.f, 0.f, 0.f, 0.f};  // 1024 floats
    }
    const float* s;
    switch (m) {
      case 0: s = s0; break; case 1: s = s1; break; case 2: s = s2; break;
      case 3: s = s3; break; case 4: s = s4; break; case 5: s = s5; break;
      case 6: s = s6; break; case 7: s = s7; break; case 8: s = s8; break;
      default: s = s9; break;
    }
    const int i = (blockIdx.x * 256 + t) * 4;
    float4 v = *(const float4*)(s + i);
    uint2 o;
    o.x = pack2(v.x, v.y);
    o.y = pack2(v.z, v.w);
    *(uint2*)(wdst + (size_t)m * 65536 + i) = o;
    return;
  }
  __shared__ u16 tile[64][65];
  const int z = yy >> 2;
  const float* x = (z < 4) ? x1 : x2;
  u16* X = (z < 4) ? X1 : X2;
  const int b = z & 3, c0 = (yy & 3) * 64, hw0 = blockIdx.x * 64;
  {
    const int hw_l = t & 63, cb = t >> 6;
#pragma unroll
    for (int i = 0; i < 16; ++i) {
      const int c_l = cb * 16 + i;
      tile[c_l][hw_l] = f2b(x[((size_t)(b * 256 + c0 + c_l)) * 4096 + hw0 + hw_l]);
    }
  }
  __syncthreads();
  {
    const int c_l = t & 63, hb = t >> 6;
#pragma unroll
    for (int i = 0; i < 16; ++i) {
      const int hw_l = hb * 16 + i;
      X[((size_t)(b * 4096 + hw0 + hw_l)) * 256 + c0 + c_l] = tile[c_l][hw_l];
    }
  }
}

// ---------- QKV GEMM: 128x128 tile (self QKV only now) ----------
// grid (NPIX/128, 6, 2): y -> group g=y>>1, slab o0=(y&1)*128; z -> stream.
struct PG { const u16* X[6]; const u16* W[3]; u16* D[6]; };

template <int NG>
__global__ void gemm_qkv(PG a) {
  __shared__ u16 As[2][8192];
  __shared__ u16 Bs[2][8192];
  const int tid = threadIdx.x;
  const int wave = tid >> 6, lane = tid & 63;
  const int p0 = blockIdx.x * 128;
  const int g = blockIdx.y >> 1, o0 = (blockIdx.y & 1) * 128;
  const int z = blockIdx.z;
  const u16* X = a.X[z * NG + g];
  const u16* W = a.W[g];
  u16* D = a.D[z * NG + g];
  const int wr = wave & 1, wc = wave >> 1;
  const int l15 = lane & 15, l4 = lane >> 4;
  const int sw = l15 & 7;
  f32x4 acc[4][4] = {};

  const u16* Xp = X + (size_t)p0 * 256;
  const u16* Wp = W + (size_t)o0 * 256;
  stage_swz<4, 256>(As[0], Xp, tid);
  stage_swz<4, 256>(Bs[0], Wp, tid);
  __syncthreads();

  for (int kt = 0; kt < 4; ++kt) {
    const int cur = kt & 1;
    if (kt < 3) {
      stage_swz<4, 256>(As[cur ^ 1], Xp + (kt + 1) * 64, tid);
      stage_swz<4, 256>(Bs[cur ^ 1], Wp + (kt + 1) * 64, tid);
    }
    compute_tile(As[cur], Bs[cur], acc, wr, wc, l15, l4, sw);
    __syncthreads();
  }
#pragma unroll
  for (int ni = 0; ni < 4; ++ni) {
    const int o = o0 + wc * 64 + ni * 16 + l15;
#pragma unroll
    for (int mi = 0; mi < 4; ++mi)
#pragma unroll
      for (int r = 0; r < 4; ++r) {
        const int p = p0 + wr * 64 + mi * 16 + l4 * 4 + r;
        D[(size_t)p * 256 + o] = f2b(acc[mi][ni][r]);
      }
  }
}

// ---------- attn_s: self attn -> fc+LN -> S -> {Qc,Kc,Vc} = S*W ----------
// grid (NPIX/128, 2), 512 threads, 132 KB LDS. The three output GEMMs are
// row-local (consume S4 from LDS), removing the separate cross-KV launch.
struct Pas { const u16* Q[2]; const u16* K[2]; const u16* V[2];
             const u16* res[2]; u16* dstS[2]; u16* dstQc[2];
             u16* dstKc[2]; u16* dstVc[2];
             const u16* Wfc; const u16* Wcq; const u16* Wck; const u16* Wcv;
             const float* g; const float* b; };

__global__ __launch_bounds__(512) void attn_s(Pas a) {
  __shared__ u16 A4[2][8192];     // 32 KB: attn-out chunks / W dbuf slot
  __shared__ u16 Bs[16384];       // 32 KB: W tile
  __shared__ u16 S4[4][8192];     // 64 KB: S tile, 4 swizzled [128][64] chunks
  __shared__ float red[2][128][4];
  const int tid = threadIdx.x;
  const int wave = tid >> 6, lane = tid & 63;
  const int wr = wave & 1, wc = wave >> 1;
  const int l15 = lane & 15, l4 = lane >> 4;
  const int sw = l15 & 7;
  const int p0 = blockIdx.x * 128;
  const int z = blockIdx.y;
  const u16* __restrict__ Q = a.Q[z];
  const u16* __restrict__ K = a.K[z];
  const u16* __restrict__ V = a.V[z];
  const u16* __restrict__ res = a.res[z];
  u16* dstS = a.dstS[z];

  const int p_l = tid >> 2, hh = tid & 3;
  const int p = p0 + p_l;
  const int yq = (p >> 6) & 63, xq = p & 63;

  bool inb[9];
  ptrdiff_t noff[9];
#pragma unroll
  for (int j = 0; j < 9; ++j) {
    const int dy = j / 3 - 1, dx = j % 3 - 1;
    inb[j] = ((unsigned)(yq + dy) < 64u) && ((unsigned)(xq + dx) < 64u);
    noff[j] = (ptrdiff_t)(dy * 64 + dx) * 256;
  }

  stage_swz<4, 512>(Bs, a.Wfc, tid);
  __builtin_amdgcn_sched_barrier(0);

  f32x4 acc[4][4] = {};
  for (int h = 0; h < 2; ++h) {
    const int head = h * 4 + hh;
    const size_t base = (size_t)p * 256 + head * 32;
    float q[32];
    {
      const uint4* qp = (const uint4*)(Q + base);
#pragma unroll
      for (int i = 0; i < 4; ++i) { uint4 w = qp[i]; unpack8(w, q + i * 8); }
    }
    float accj[9];
#pragma unroll
    for (int j = 0; j < 9; ++j) accj[j] = 0.f;
#pragma unroll
    for (int i = 0; i < 4; ++i) {
      uint4 w[9];
#pragma unroll
      for (int j = 0; j < 9; ++j)
        if (inb[j]) w[j] = ((const uint4*)(K + base + noff[j]))[i];
#pragma unroll
      for (int j = 0; j < 9; ++j) {
        if (inb[j]) {
          float kf[8]; unpack8(w[j], kf);
#pragma unroll
          for (int d = 0; d < 8; ++d) accj[j] += q[i * 8 + d] * kf[d];
        }
      }
    }
    float lg[9];
    float mx = -1e30f;
#pragma unroll
    for (int j = 0; j < 9; ++j) {
      const float l = inb[j] ? accj[j] * 0.17677669529663687f : 0.f;
      lg[j] = l;
      mx = fmaxf(mx, l);
    }
    float pr[9], den = 0.f;
#pragma unroll
    for (int j = 0; j < 9; ++j) { pr[j] = __expf(lg[j] - mx); den += pr[j]; }
    float out[32];
#pragma unroll
    for (int d = 0; d < 32; ++d) out[d] = 0.f;
#pragma unroll
    for (int i = 0; i < 4; ++i) {
      uint4 w[9];
#pragma unroll
      for (int j = 0; j < 9; ++j)
        if (inb[j]) w[j] = ((const uint4*)(V + base + noff[j]))[i];
#pragma unroll
      for (int j = 0; j < 9; ++j) {
        if (inb[j]) {
          float vf[8]; unpack8(w[j], vf);
          const float pw = pr[j];
#pragma unroll
          for (int d = 0; d < 8; ++d) out[i * 8 + d] += pw * vf[d];
        }
      }
    }
    const float inv = 1.f / den;
#pragma unroll
    for (int i = 0; i < 4; ++i) {
      uint4 w;
      w.x = pack2(out[i * 8 + 0] * inv, out[i * 8 + 1] * inv);
      w.y = pack2(out[i * 8 + 2] * inv, out[i * 8 + 3] * inv);
      w.z = pack2(out[i * 8 + 4] * inv, out[i * 8 + 5] * inv);
      w.w = pack2(out[i * 8 + 6] * inv, out[i * 8 + 7] * inv);
      const int c8g = hh * 4 + i;
      const int sub = c8g >> 3, c8in = c8g & 7;
      *(uint4*)&A4[sub][p_l * 64 + ((c8in ^ (p_l & 7)) * 8)] = w;
    }

    __syncthreads();
    compute_tile(A4[0], Bs, acc, wr, wc, l15, l4, sw);
    __syncthreads();
    stage_swz<4, 512>(Bs, a.Wfc + (h * 2 + 1) * 64, tid);
    __syncthreads();
    compute_tile(A4[1], Bs, acc, wr, wc, l15, l4, sw);
    __syncthreads();
    if (h == 0) {
      stage_swz<4, 512>(Bs, a.Wfc + 2 * 64, tid);
      __builtin_amdgcn_sched_barrier(0);
    }
  }

  // stage Wcq k0 under the LN epilogue (Bs free now)
  stage_swz<4, 512>(Bs, a.Wcq, tid);
  __builtin_amdgcn_sched_barrier(0);

  // residual + per-pixel LN -> dstS global + S4 LDS
#pragma unroll
  for (int mi = 0; mi < 4; ++mi) {
#pragma unroll
    for (int r = 0; r < 4; ++r) {
      const int pl = wr * 64 + mi * 16 + l4 * 4 + r;
      const int pp = p0 + pl;
      float s = 0.f, s2 = 0.f;
#pragma unroll
      for (int ni = 0; ni < 4; ++ni) {
        const int o = wc * 64 + ni * 16 + l15;
        float vv = acc[mi][ni][r] + b2f(res[(size_t)pp * 256 + o]);
        acc[mi][ni][r] = vv;
        s += vv; s2 += vv * vv;
      }
#pragma unroll
      for (int m = 1; m < 16; m <<= 1) {
        s += __shfl_xor(s, m); s2 += __shfl_xor(s2, m);
      }
      if (l15 == 0) { red[0][pl][wc] = s; red[1][pl][wc] = s2; }
    }
  }
  __syncthreads();

  float gv[4], bv[4];
#pragma unroll
  for (int ni = 0; ni < 4; ++ni) {
    const int o = wc * 64 + ni * 16 + l15;
    gv[ni] = a.g[o]; bv[ni] = a.b[o];
  }
#pragma unroll
  for (int mi = 0; mi < 4; ++mi) {
#pragma unroll
    for (int r = 0; r < 4; ++r) {
      const int pl = wr * 64 + mi * 16 + l4 * 4 + r;
      const float st = red[0][pl][0] + red[0][pl][1] + red[0][pl][2] + red[0][pl][3];
      const float s2t = red[1][pl][0] + red[1][pl][1] + red[1][pl][2] + red[1][pl][3];
      const float mu = st * (1.f / 256.f);
      const float var = s2t * (1.f / 256.f) - mu * mu;
      const float inv = rsqrtf(var + 1e-6f);
      const int pp = p0 + pl;
#pragma unroll
      for (int ni = 0; ni < 4; ++ni) {
        const int o = wc * 64 + ni * 16 + l15;
        const u16 hv = f2b((acc[mi][ni][r] - mu) * inv * gv[ni] + bv[ni]);
        dstS[(size_t)pp * 256 + o] = hv;
        const int c8 = (ni * 16 + l15) >> 3;
        S4[wc][pl * 64 + ((c8 ^ (pl & 7)) * 8) + (l15 & 7)] = hv;
      }
    }
  }
  __syncthreads();   // S4 complete; Wcq k0 loaded (barrier drains vmcnt)

  // {Qc, Kc, Vc} = S * {Wcq, Wck, Wcv}: 12 K-steps, W ping-pong Bs/a4f.
  // g-th step uses buffer (g&1 ? A4 : Bs); stage g+1 before compute(g).
  u16* a4f = &A4[0][0];
  const u16* Ws[3] = {a.Wcq, a.Wck, a.Wcv};
  u16* dsts[3] = {a.dstQc[z], a.dstKc[z], a.dstVc[z]};
#pragma unroll
  for (int gq = 0; gq < 3; ++gq) {
    f32x4 accq[4][4] = {};
#pragma unroll
    for (int kt = 0; kt < 4; ++kt) {
      const int g = gq * 4 + kt;
      if (g < 11) {
        const int gn = g + 1;
        stage_swz<4, 512>((gn & 1) ? a4f : Bs, Ws[gn >> 2] + (gn & 3) * 64, tid);
      }
      compute_tile(&S4[kt][0], (g & 1) ? a4f : Bs, accq, wr, wc, l15, l4, sw);
      __syncthreads();
    }
    u16* D = dsts[gq];
#pragma unroll
    for (int ni = 0; ni < 4; ++ni) {
      const int o = wc * 64 + ni * 16 + l15;
#pragma unroll
      for (int mi = 0; mi < 4; ++mi)
#pragma unroll
        for (int r = 0; r < 4; ++r) {
          const int pp = p0 + wr * 64 + mi * 16 + l4 * 4 + r;
          D[(size_t)pp * 256 + o] = f2b(accq[mi][ni][r]);
        }
    }
  }
}

// ---------- attn_c_ffn: cross attn -> fc+LN -> C -> FFN -> U + stats ------
// grid (NPIX/128, 2), 512 threads, 132 KB LDS.
struct Pcf { const u16* Q[2]; const u16* K[2]; const u16* V[2];
             const u16* resS[2]; u16* dstC[2]; u16* U[2]; float* st[2];
             const u16* Wfc; const float* g; const float* b;
             const u16* W1; const float* bb1; const u16* W2; const float* bb2; };

__global__ __launch_bounds__(512) void attn_c_ffn(Pcf a) {
  __shared__ u16 A4[2][8192];     // 32 KB
  __shared__ u16 Bs[16384];       // 32 KB
  __shared__ u16 M4[4][8192];     // 64 KB: C tile, then relu'd mid
  __shared__ float red[2][128][4];
  const int tid = threadIdx.x;
  const int wave = tid >> 6, lane = tid & 63;
  const int wr = wave & 1, wc = wave >> 1;
  const int l15 = lane & 15, l4 = lane >> 4;
  const int sw = l15 & 7;
  const int p0 = blockIdx.x * 128;
  const int z = blockIdx.y;
  const u16* __restrict__ Q = a.Q[z];
  const u16* __restrict__ K = a.K[z];
  const u16* __restrict__ V = a.V[z];
  const u16* __restrict__ resS = a.resS[z];
  u16* dstC = a.dstC[z];
  u16* U = a.U[z];
  float* st = a.st[z];

  const int p_l = tid >> 2, hh = tid & 3;
  const int p = p0 + p_l;
  const int yq = (p >> 6) & 63, xq = p & 63;

  bool inb[9];
  ptrdiff_t noff[9];
#pragma unroll
  for (int j = 0; j < 9; ++j) {
    const int dy = j / 3 - 1, dx = j % 3 - 1;
    inb[j] = ((unsigned)(yq + dy) < 64u) && ((unsigned)(xq + dx) < 64u);
    noff[j] = (ptrdiff_t)(dy * 64 + dx) * 256;
  }

  stage_swz<4, 512>(Bs, a.Wfc, tid);
  __builtin_amdgcn_sched_barrier(0);

  f32x4 acc[4][4] = {};
  for (int h = 0; h < 2; ++h) {
    const int head = h * 4 + hh;
    const size_t base = (size_t)p * 256 + head * 32;
    float q[32];
    {
      const uint4* qp = (const uint4*)(Q + base);
#pragma unroll
      for (int i = 0; i < 4; ++i) { uint4 w = qp[i]; unpack8(w, q + i * 8); }
    }
    float accj[9];
#pragma unroll
    for (int j = 0; j < 9; ++j) accj[j] = 0.f;
#pragma unroll
    for (int i = 0; i < 4; ++i) {
      uint4 w[9];
#pragma unroll
      for (int j = 0; j < 9; ++j)
        if (inb[j]) w[j] = ((const uint4*)(K + base + noff[j]))[i];
#pragma unroll
      for (int j = 0; j < 9; ++j) {
        if (inb[j]) {
          float kf[8]; unpack8(w[j], kf);
#pragma unroll
          for (int d = 0; d < 8; ++d) accj[j] += q[i * 8 + d] * kf[d];
        }
      }
    }
    float lg[9];
    float mx = -1e30f;
#pragma unroll
    for (int j = 0; j < 9; ++j) {
      const float l = inb[j] ? accj[j] * 0.17677669529663687f : 0.f;
      lg[j] = l;
      mx = fmaxf(mx, l);
    }
    float pr[9], den = 0.f;
#pragma unroll
    for (int j = 0; j < 9; ++j) { pr[j] = __expf(lg[j] - mx); den += pr[j]; }
    float out[32];
#pragma unroll
    for (int d = 0; d < 32; ++d) out[d] = 0.f;
#pragma unroll
    for (int i = 0; i < 4; ++i) {
      uint4 w[9];
#pragma unroll
      for (int j = 0; j < 9; ++j)
        if (inb[j]) w[j] = ((const uint4*)(V + base + noff[j]))[i];
#pragma unroll
      for (int j = 0; j < 9; ++j) {
        if (inb[j]) {
          float vf[8]; unpack8(w[j], vf);
          const float pw = pr[j];
#pragma unroll
          for (int d = 0; d < 8; ++d) out[i * 8 + d] += pw * vf[d];
        }
      }
    }
    const float inv = 1.f / den;
#pragma unroll
    for (int i = 0; i < 4; ++i) {
      uint4 w;
      w.x = pack2(out[i * 8 + 0] * inv, out[i * 8 + 1] * inv);
      w.y = pack2(out[i * 8 + 2] * inv, out[i * 8 + 3] * inv);
      w.z = pack2(out[i * 8 + 4] * inv, out[i * 8 + 5] * inv);
      w.w = pack2(out[i * 8 + 6] * inv, out[i * 8 + 7] * inv);
      const int c8g = hh * 4 + i;
      const int sub = c8g >> 3, c8in = c8g & 7;
      *(uint4*)&A4[sub][p_l * 64 + ((c8in ^ (p_l & 7)) * 8)] = w;
    }

    __syncthreads();
    compute_tile(A4[0], Bs, acc, wr, wc, l15, l4, sw);
    __syncthreads();
    stage_swz<4, 512>(Bs, a.Wfc + (h * 2 + 1) * 64, tid);
    __syncthreads();
    compute_tile(A4[1], Bs, acc, wr, wc, l15, l4, sw);
    __syncthreads();
    if (h == 0) {
      stage_swz<4, 512>(Bs, a.Wfc + 2 * 64, tid);
      __builtin_amdgcn_sched_barrier(0);
    }
  }

  // stage W1 k0 under the LN epilogue
  stage_swz<4, 512>(Bs, a.W1, tid);
  __builtin_amdgcn_sched_barrier(0);

  // residual + LN -> dstC global + M4 LDS
#pragma unroll
  for (int mi = 0; mi < 4; ++mi) {
#pragma unroll
    for (int r = 0; r < 4; ++r) {
      const int pl = wr * 64 + mi * 16 + l4 * 4 + r;
      const int pp = p0 + pl;
      float s = 0.f, s2 = 0.f;
#pragma unroll
      for (int ni = 0; ni < 4; ++ni) {
        const int o = wc * 64 + ni * 16 + l15;
        float vv = acc[mi][ni][r] + b2f(resS[(size_t)pp * 256 + o]);
        acc[mi][ni][r] = vv;
        s += vv; s2 += vv * vv;
      }
#pragma unroll
      for (int m = 1; m < 16; m <<= 1) {
        s += __shfl_xor(s, m); s2 += __shfl_xor(s2, m);
      }
      if (l15 == 0) { red[0][pl][wc] = s; red[1][pl][wc] = s2; }
    }
  }
  __syncthreads();

  float gv[4], bv[4];
#pragma unroll
  for (int ni = 0; ni < 4; ++ni) {
    const int o = wc * 64 + ni * 16 + l15;
    gv[ni] = a.g[o]; bv[ni] = a.b[o];
  }
#pragma unroll
  for (int mi = 0; mi < 4; ++mi) {
#pragma unroll
    for (int r = 0; r < 4; ++r) {
      const int pl = wr * 64 + mi * 16 + l4 * 4 + r;
      const float st2 = red[0][pl][0] + red[0][pl][1] + red[0][pl][2] + red[0][pl][3];
      const float s2t = red[1][pl][0] + red[1][pl][1] + red[1][pl][2] + red[1][pl][3];
      const float mu = st2 * (1.f / 256.f);
      const float var = s2t * (1.f / 256.f) - mu * mu;
      const float inv = rsqrtf(var + 1e-6f);
      const int pp = p0 + pl;
#pragma unroll
      for (int ni = 0; ni < 4; ++ni) {
        const int o = wc * 64 + ni * 16 + l15;
        const u16 hv = f2b((acc[mi][ni][r] - mu) * inv * gv[ni] + bv[ni]);
        dstC[(size_t)pp * 256 + o] = hv;
        const int c8 = (ni * 16 + l15) >> 3;
        M4[wc][pl * 64 + ((c8 ^ (pl & 7)) * 8) + (l15 & 7)] = hv;
      }
    }
  }
  __syncthreads();   // M4(C) complete; W1 k0 loaded

  u16* a4f = &A4[0][0];
  // ffn1: acc1 = C*W1
  f32x4 acc1[4][4] = {};
  for (int kt = 0; kt < 4; ++kt) {
    if (kt < 3)
      stage_swz<4, 512>(((kt + 1) & 1) ? a4f : Bs, a.W1 + (kt + 1) * 64, tid);
    compute_tile(&M4[kt][0], (kt & 1) ? a4f : Bs, acc1, wr, wc, l15, l4, sw);
    __syncthreads();
  }
  // stage W2 k0 under mid epilogue (Bs free: last compute used A4)
  stage_swz<4, 512>(Bs, a.W2, tid);
  __builtin_amdgcn_sched_barrier(0);
  // mid = relu(acc1 + b1) -> overwrite M4 (chunk wc)
  {
    float bvv[4];
#pragma unroll
    for (int ni = 0; ni < 4; ++ni) bvv[ni] = a.bb1[wc * 64 + ni * 16 + l15];
    u16* ml = &M4[wc][0];
#pragma unroll
    for (int mi = 0; mi < 4; ++mi) {
#pragma unroll
      for (int r = 0; r < 4; ++r) {
        const int pl = wr * 64 + mi * 16 + l4 * 4 + r;
#pragma unroll
        for (int ni = 0; ni < 4; ++ni) {
          const int col = ni * 16 + l15;
          const int c8 = col >> 3;
          const u16 hv = f2b(fmaxf(acc1[mi][ni][r] + bvv[ni], 0.f));
          ml[pl * 64 + ((c8 ^ (pl & 7)) * 8) + (col & 7)] = hv;
        }
      }
    }
  }
  __syncthreads();   // mid visible; W2 k0 loaded

  // ffn2: U = mid*W2 + b2, stats on bf16-rounded values
  f32x4 acc2[4][4] = {};
  for (int kt = 0; kt < 4; ++kt) {
    if (kt < 3)
      stage_swz<4, 512>(((kt + 1) & 1) ? a4f : Bs, a.W2 + (kt + 1) * 64, tid);
    compute_tile(&M4[kt][0], (kt & 1) ? a4f : Bs, acc2, wr, wc, l15, l4, sw);
    __syncthreads();
  }
#pragma unroll
  for (int ni = 0; ni < 4; ++ni) {
    const int o = wc * 64 + ni * 16 + l15;
    const float bvv = a.bb2[o];
    float s = 0.f, s2 = 0.f;
#pragma unroll
    for (int mi = 0; mi < 4; ++mi) {
#pragma unroll
      for (int r = 0; r < 4; ++r) {
        const int pp = p0 + wr * 64 + mi * 16 + l4 * 4 + r;
        const u16 hv = f2b(acc2[mi][ni][r] + bvv);
        U[(size_t)pp * 256 + o] = hv;
        const float vr = b2f(hv); s += vr; s2 += vr * vr;
      }
    }
    s += __shfl_xor(s, 16); s2 += __shfl_xor(s2, 16);
    s += __shfl_xor(s, 32); s2 += __shfl_xor(s2, 32);
    if (l4 == 0) { atomicAdd(&st[o], s); atomicAdd(&st[256 + o], s2); }
  }
}

// ---------- BN apply + residual + transpose back to fp32 [B,C,H,W] ----------
struct Pbn { const u16* U[2]; const u16* res[2]; const float* st[2];
             float* out[2]; const float* g; const float* b; };

__global__ void bn_apply(Pbn a) {
  __shared__ float tile[64][65];
  const int t = threadIdx.x;
  const int s = blockIdx.z >> 2, b = blockIdx.z & 3;
  const u16* __restrict__ U = a.U[s];
  const u16* __restrict__ res = a.res[s];
  const float* st = a.st[s];
  float* out = a.out[s];
  const int c0 = blockIdx.y * 64, hw0 = blockIdx.x * 64;
  {
    const int c_l = t & 63, hb = t >> 6;
    const int c = c0 + c_l;
    const float mu = st[c] * (1.f / 16384.f);
    const float var = st[256 + c] * (1.f / 16384.f) - mu * mu;
    const float sc = rsqrtf(var + 1e-5f) * a.g[c];
    const float sh = a.b[c] - mu * sc;
#pragma unroll
    for (int i = 0; i < 16; ++i) {
      const int hw_l = hb * 16 + i;
      const size_t p = (size_t)b * 4096 + hw0 + hw_l;
      const float u = b2f(U[p * 256 + c]);
      const float r = b2f(res[p * 256 + c]);
      tile[hw_l][c_l] = u * sc + sh + r;
    }
  }
  __syncthreads();
  {
    const int hw_l = t & 63, cb2 = t >> 6;
#pragma unroll
    for (int i = 0; i < 16; ++i) {
      const int c_l = cb2 * 16 + i;
      out[((size_t)(b * 256 + c0 + c_l)) * 4096 + hw0 + hw_l] = tile[hw_l][c_l];
    }
  }
}

extern "C" void kernel_launch(void* const* d_in, const int* in_sizes, int n_in,
                              void* d_out, int out_size, void* d_ws, size_t ws_size,
                              hipStream_t stream) {
  const float* input1 = (const float*)d_in[0];
  const float* input2 = (const float*)d_in[1];
  const float* slf_wq = (const float*)d_in[2];
  const float* slf_wk = (const float*)d_in[3];
  const float* slf_wv = (const float*)d_in[4];
  const float* slf_fc = (const float*)d_in[5];
  const float* slf_g  = (const float*)d_in[6];
  const float* slf_b  = (const float*)d_in[7];
  const float* crs_wq = (const float*)d_in[8];
  const float* crs_wk = (const float*)d_in[9];
  const float* crs_wv = (const float*)d_in[10];
  const float* crs_fc = (const float*)d_in[11];
  const float* crs_g  = (const float*)d_in[12];
  const float* crs_b  = (const float*)d_in[13];
  const float* ffn_w1 = (const float*)d_in[14];
  const float* ffn_b1 = (const float*)d_in[15];
  const float* ffn_w2 = (const float*)d_in[16];
  const float* ffn_b2 = (const float*)d_in[17];
  const float* bn_g   = (const float*)d_in[18];
  const float* bn_b   = (const float*)d_in[19];

  float* out = (float*)d_out;
  u16* ws = (u16*)d_ws;
  const size_t TS = (size_t)NPIX * CDIM;  // 8 MB bf16
  u16* b[12];
  for (int i = 0; i < 12; ++i) b[i] = ws + (size_t)i * TS;
  u16* wb = ws + 12 * TS;                 // 10 * 65536 bf16 weights
  u16 *Wsq = wb,             *Wsk = wb + 65536,     *Wsv = wb + 2 * 65536,
      *Wsf = wb + 3 * 65536, *Wcq = wb + 4 * 65536, *Wck = wb + 5 * 65536,
      *Wcv = wb + 6 * 65536, *Wcf = wb + 7 * 65536, *W1 = wb + 8 * 65536,
      *W2 = wb + 9 * 65536;
  float* stats = (float*)(wb + 10 * 65536);  // 2 x 512 floats

  const dim3 tb(256);

  prep<<<dim3(64, 42), tb, 0, stream>>>(input1, input2, b[0], b[1],
                                        slf_wq, slf_wk, slf_wv, slf_fc,
                                        crs_wq, crs_wk, crs_wv, crs_fc,
                                        ffn_w1, ffn_w2, wb, stats);

  // ---- self QKV ----
  PG sa;
  sa.X[0] = b[0]; sa.X[1] = b[0]; sa.X[2] = b[0];
  sa.X[3] = b[1]; sa.X[4] = b[1]; sa.X[5] = b[1];
  sa.W[0] = Wsq; sa.W[1] = Wsk; sa.W[2] = Wsv;
  sa.D[0] = b[4]; sa.D[1] = b[5]; sa.D[2] = b[6];
  sa.D[3] = b[7]; sa.D[4] = b[8]; sa.D[5] = b[9];
  gemm_qkv<3><<<dim3(NPIX / 128, 6, 2), tb, 0, stream>>>(sa);

  // ---- self attn + fc/LN -> S, + cross Q/K/V (row-local from LDS S) ----
  Pas f1;
  f1.Q[0] = b[4]; f1.K[0] = b[5]; f1.V[0] = b[6];
  f1.Q[1] = b[7]; f1.K[1] = b[8]; f1.V[1] = b[9];
  f1.res[0] = b[0]; f1.res[1] = b[1];
  f1.dstS[0] = b[2]; f1.dstS[1] = b[3];
  f1.dstQc[0] = b[4]; f1.dstQc[1] = b[7];   // row-local overwrite of self-Q
  f1.dstKc[0] = b[0]; f1.dstKc[1] = b[1];   // row-local overwrite of X (res read first)
  f1.dstVc[0] = b[10]; f1.dstVc[1] = b[11]; // fresh buffers
  f1.Wfc = Wsf; f1.Wcq = Wcq; f1.Wck = Wck; f1.Wcv = Wcv;
  f1.g = slf_g; f1.b = slf_b;
  attn_s<<<dim3(NPIX / 128, 2), dim3(512), 0, stream>>>(f1);

  // ---- cross attn + fc/LN -> C, + FFN -> U + stats ----
  // C1 = mha(q=S1, kv=S2): Q=Qc(S1)=b4, K=Kc(S2)=b1, V=Vc(S2)=b11
  // C2 = mha(q=S2, kv=S1): Q=Qc(S2)=b7, K=Kc(S1)=b0, V=Vc(S1)=b10
  Pcf f2;
  f2.Q[0] = b[4]; f2.K[0] = b[1]; f2.V[0] = b[11];
  f2.Q[1] = b[7]; f2.K[1] = b[0]; f2.V[1] = b[10];
  f2.resS[0] = b[2]; f2.resS[1] = b[3];
  f2.dstC[0] = b[5]; f2.dstC[1] = b[8];     // self-K buffers, dead now
  f2.U[0] = b[2]; f2.U[1] = b[3];           // row-local overwrite of S
  f2.st[0] = stats; f2.st[1] = stats + 512;
  f2.Wfc = Wcf; f2.g = crs_g; f2.b = crs_b;
  f2.W1 = W1; f2.bb1 = ffn_b1; f2.W2 = W2; f2.bb2 = ffn_b2;
  attn_c_ffn<<<dim3(NPIX / 128, 2), dim3(512), 0, stream>>>(f2);

  Pbn bn;
  bn.U[0] = b[2]; bn.U[1] = b[3];
  bn.res[0] = b[5]; bn.res[1] = b[8];
  bn.st[0] = stats; bn.st[1] = stats + 512;
  bn.out[0] = out; bn.out[1] = out + TS;
  bn.g = bn_g; bn.b = bn_b;
  bn_apply<<<dim3(64, 4, 8), tb, 0, stream>>>(bn);
}